// Round 10
// baseline (3602.562 us; speedup 1.0000x reference)
//
#include <hip/hip_runtime.h>
#include <hip/hip_bf16.h>

#define B_ 32
#define T_ 512
#define E_ 256
#define H_ 512
#define L_ 50
#define V_ 50000
#define NBLK 32          // worker blocks (placement-independent protocol)
#define NGRID 32         // exactly the workers — no election, no spinners
#define NWFLAG 128       // per-WAVE flags (32 blocks x 4 waves), dword each

typedef __attribute__((ext_vector_type(8))) short short8;
typedef __attribute__((ext_vector_type(4))) float v4f;
typedef __attribute__((ext_vector_type(4))) int i4;
typedef unsigned long long u64;

__device__ __forceinline__ unsigned short f2bf(float f){
    union { float f; unsigned u; } v; v.f = f;
    unsigned u = v.u;
    u += 0x7fffu + ((u >> 16) & 1u);   // RNE
    return (unsigned short)(u >> 16);
}
// native-transcendental activations: v_exp_f32 + v_rcp_f32 (~1e-6 rel err, far
// below the bf16 rounding already in the h pipeline; validated absmax=0 r2-r9)
__device__ __forceinline__ float fastsig(float x){
    return __builtin_amdgcn_rcpf(1.0f + __expf(-x));
}
__device__ __forceinline__ float fasttanh(float x){
    return 1.0f - 2.0f * __builtin_amdgcn_rcpf(__expf(2.0f * x) + 1.0f);
}

__device__ __forceinline__ float qredmax(float v){
    v = fmaxf(v, __shfl_xor(v, 1, 64));
    v = fmaxf(v, __shfl_xor(v, 2, 64));
    v = fmaxf(v, __shfl_xor(v, 4, 64));
    v = fmaxf(v, __shfl_xor(v, 8, 64));
    return v;
}
__device__ __forceinline__ float qredsum(float v){
    v += __shfl_xor(v, 1, 64);
    v += __shfl_xor(v, 2, 64);
    v += __shfl_xor(v, 4, 64);
    v += __shfl_xor(v, 8, 64);
    return v;
}

// DEVICE-coherent memory ops: sc0 sc1 = bypass L1 AND L2, coherence point is
// the MALL. Placement-independent (r9-proven): works no matter which XCDs the
// worker blocks land on.
__device__ __forceinline__ i4 load16_dev(const void* p){
    i4 r;
    asm volatile("global_load_dwordx4 %0, %1, off sc0 sc1" : "=v"(r) : "v"(p) : "memory");
    return r;
}
__device__ __forceinline__ void store8_dev(void* p, u64 v){
    asm volatile("global_store_dwordx2 %0, %1, off sc0 sc1" : : "v"(p), "v"(v) : "memory");
}
__device__ __forceinline__ void store4_dev(void* p, unsigned v){
    asm volatile("global_store_dword %0, %1, off sc0 sc1" : : "v"(p), "v"(v) : "memory");
}
__device__ __forceinline__ unsigned load4_dev_nowait(const void* p){
    unsigned r;
    asm volatile("global_load_dword %0, %1, off sc0 sc1" : "=v"(r) : "v"(p) : "memory");
    return r;
}
__device__ __forceinline__ void wait_vm0(){
    asm volatile("s_waitcnt vmcnt(0)" ::: "memory");
}

// ---------------------------------------------------------------- init + we->bf16 convert
// grid 6400 x 256 = 1,638,400 threads; each converts 8 floats of word_embed.
__global__ void init_kernel(const float* __restrict__ projW,
                            const float* __restrict__ we,
                            float* __restrict__ out,
                            unsigned int* __restrict__ setup,   // reserved (unused this round)
                            unsigned int* __restrict__ flags,   // [NWFLAG] monotonic step tags
                            unsigned short* __restrict__ h0,
                            unsigned short* __restrict__ Wt,
                            unsigned short* __restrict__ we_bf)
{
    const int i = blockIdx.x * 256 + threadIdx.x;
    if (i < 1024) setup[i] = 0u;
    if (i < NWFLAG) flags[i] = 0u;
    if (i == 0) out[0] = 0.f;
    if (i < B_ * H_) h0[i] = 0;                     // h_all step 0 = zeros
    if (i < 64 * H_){                               // Wt[c][k] = proj_W[k][c], bf16, pad c>=50 with 0
        const int c = i >> 9;
        const int k = i & 511;
        const float v = (c < L_) ? projW[k * L_ + c] : 0.f;
        Wt[i] = f2bf(v);
    }
    if (i < (V_ * E_) / 8){                         // bf16 embedding table (same RNE as before)
        const v4f* src = (const v4f*)(we + (size_t)i * 8);
        const v4f a = src[0], b = src[1];
        short8 o;
#pragma unroll
        for (int j = 0; j < 4; ++j){ o[j] = (short)f2bf(a[j]); o[4 + j] = (short)f2bf(b[j]); }
        *(short8*)(we_bf + (size_t)i * 8) = o;
    }
}

// ---------------------------------------------------------------- LSTM recurrence (cooperative, device-coherent)
// Base: r9's placement-robust sc0 sc1 protocol (proven 2425us, any placement).
// Round-10 deltas (both previously failed ONLY due to the sc0-staleness root
// cause that sc1 eliminates):
//  * PER-WAVE dword flags (128/step): each wave stores its h chunk -> vmcnt0
//    ack -> stores flags[blk*4+wv]=t+1. __syncthreads leaves the loop.
//    Consumers poll 2 flags per lane (lane, lane+64).
//  * POLL PRE-ISSUE: the 2 flag loads for step t+1 are issued right after our
//    own flag store; their MALL RT overlaps the tail MFMAs. Top-of-loop:
//    vmcnt0 + ballot; fallback sleep-poll only if some producer genuinely
//    lags (sc1 loads cannot read stale data, so a miss means "not done yet").
__global__ void __launch_bounds__(256, 1) lstm_kernel(
    const int* __restrict__ q, const int* __restrict__ lengths,
    const unsigned short* __restrict__ we_bf, const float* __restrict__ lstmW,
    const float* __restrict__ lstmB,
    unsigned short* __restrict__ h_all, unsigned int* __restrict__ flags)
{
    const int tid  = threadIdx.x;
    const int blk  = blockIdx.x;     // worker slot 0..31

    const int wv   = tid >> 6;       // 0..3
    const int lane = tid & 63;
    const int nt = wv & 1, mpair = wv >> 1;   // n-half, m-tile pair
    const int l15 = lane & 15, quad = lane >> 4;

    // ---- A-operand mapping (lane&15 = m = z-col in tile; k = quad*8 + j)
    const int hcA0 = blk * 16 + (mpair * 2 + 0) * 4 + (l15 >> 2);
    const int hcA1 = blk * 16 + (mpair * 2 + 1) * 4 + (l15 >> 2);
    const int gA   = l15 & 3;
    const int colA0 = gA * H_ + hcA0;
    const int colA1 = gA * H_ + hcA1;

    short8 AW0[8], AW1[8], AH0[16], AH1[16];
#pragma unroll
    for (int kc = 0; kc < 8; ++kc){     // x-part rows 0..255
        short8 f0, f1;
#pragma unroll
        for (int j = 0; j < 8; ++j){
            const int r = kc * 32 + quad * 8 + j;
            f0[j] = (short)f2bf(lstmW[(size_t)r * 2048 + colA0]);
            f1[j] = (short)f2bf(lstmW[(size_t)r * 2048 + colA1]);
        }
        AW0[kc] = f0; AW1[kc] = f1;
    }
#pragma unroll
    for (int kc = 0; kc < 16; ++kc){    // h-part rows 256..767
        short8 f0, f1;
#pragma unroll
        for (int j = 0; j < 8; ++j){
            const int r = E_ + kc * 32 + quad * 8 + j;
            f0[j] = (short)f2bf(lstmW[(size_t)r * 2048 + colA0]);
            f1[j] = (short)f2bf(lstmW[(size_t)r * 2048 + colA1]);
        }
        AH0[kc] = f0; AH1[kc] = f1;
    }

    // ---- epilogue mapping (lane&15 = n = batch; D row quad*4+reg -> hc=quad, gate=reg)
    const int bE   = nt * 16 + l15;
    const int hcE0 = blk * 16 + (mpair * 2 + 0) * 4 + quad;
    const int hcE1 = blk * 16 + (mpair * 2 + 1) * 4 + quad;
    float bias0[4], bias1[4];
#pragma unroll
    for (int g = 0; g < 4; ++g){ bias0[g] = lstmB[g * H_ + hcE0]; bias1[g] = lstmB[g * H_ + hcE1]; }
    const int lenb = lengths[bE];

    float c0 = 0.f, c1 = 0.f, hp0 = 0.f, hp1 = 0.f;

    // pre-loop x-part for t=0 (cold path)
    v4f accX0 = { bias0[0], bias0[1], bias0[2], bias0[3] };
    v4f accX1 = { bias1[0], bias1[1], bias1[2], bias1[3] };
    {
        const int qv = q[bE * T_];
        const short8* wp = (const short8*)(we_bf + (size_t)qv * E_);
#pragma unroll
        for (int kc = 0; kc < 8; ++kc){
            const short8 eb = wp[kc * 4 + quad];
            accX0 = __builtin_amdgcn_mfma_f32_16x16x32_bf16(AW0[kc], eb, accX0, 0, 0, 0);
            accX1 = __builtin_amdgcn_mfma_f32_16x16x32_bf16(AW1[kc], eb, accX1, 0, 0, 0);
        }
    }

    int qnext = q[bE * T_ + 1];      // q for t+1 (prefetched one iter ahead)
    unsigned pv0 = 0u, pv1 = 0u;     // pre-issued flag values

    for (int t = 0; t < T_; ++t){
        // (B) poll check: pv0/pv1 were pre-issued after our flag store; their
        // MALL RT overlapped the tail. One vmcnt0 + ballot in the common case.
        if (t > 0){
            wait_vm0();
            if (__ballot(pv0 >= (unsigned)t && pv1 >= (unsigned)t) != 0xFFFFFFFFFFFFFFFFull){
                int guard = 0;
                for (;;){
                    unsigned f0, f1;
                    asm volatile(
                        "global_load_dword %0, %2, off sc0 sc1\n\t"
                        "global_load_dword %1, %3, off sc0 sc1\n\t"
                        "s_waitcnt vmcnt(0)"
                        : "=v"(f0), "=v"(f1)
                        : "v"(flags + lane), "v"(flags + lane + 64) : "memory");
                    if (__ballot(f0 >= (unsigned)t && f1 >= (unsigned)t) == 0xFFFFFFFFFFFFFFFFull)
                        break;
                    __builtin_amdgcn_s_sleep(1);
                    if (++guard > (1 << 16)) break;   // safety valve
                }
            }
        }

        // (C) all 16 h B-frag loads from the MALL, ONE wait
        const unsigned short* hrow = h_all + (size_t)t * (B_ * H_) + (size_t)bE * H_;
        i4 hbuf[16];
#pragma unroll
        for (int kc = 0; kc < 16; ++kc)
            hbuf[kc] = load16_dev(hrow + kc * 32 + quad * 8);
        wait_vm0();

        // (A) issue bf16 x-row loads for t+1 NOW (plain cached loads): RT
        // hides under the 32 MFMA + gates below; drained by (F)'s ack wait.
        short8 xe[8];
        {
            const short8* wp = (const short8*)(we_bf + (size_t)qnext * E_);
#pragma unroll
            for (int kc = 0; kc < 8; ++kc) xe[kc] = wp[kc * 4 + quad];
        }
        const int qnext2 = q[bE * T_ + ((t + 2 < T_) ? (t + 2) : (T_ - 1))];

        // (D) 32 MFMA in 4 independent chains (kc even/odd x 2 tiles)
        v4f a0e = accX0, a1e = accX1;
        v4f a0o = { 0.f, 0.f, 0.f, 0.f }, a1o = { 0.f, 0.f, 0.f, 0.f };
#pragma unroll
        for (int kc = 0; kc < 16; kc += 2){
            union { i4 i; short8 s; } cv0, cv1; cv0.i = hbuf[kc]; cv1.i = hbuf[kc + 1];
            a0e = __builtin_amdgcn_mfma_f32_16x16x32_bf16(AH0[kc],     cv0.s, a0e, 0, 0, 0);
            a1e = __builtin_amdgcn_mfma_f32_16x16x32_bf16(AH1[kc],     cv0.s, a1e, 0, 0, 0);
            a0o = __builtin_amdgcn_mfma_f32_16x16x32_bf16(AH0[kc + 1], cv1.s, a0o, 0, 0, 0);
            a1o = __builtin_amdgcn_mfma_f32_16x16x32_bf16(AH1[kc + 1], cv1.s, a1o, 0, 0, 0);
        }
        const v4f acc0 = a0e + a0o;
        const v4f acc1 = a1e + a1o;

        // (E) gates per tile: i,j,f,o = acc[0..3]; native exp/rcp
        const bool msk = (t < lenb);
        const float cn0 = c0 * fastsig(acc0[2] + 1.0f) + fastsig(acc0[0]) * fasttanh(acc0[1]);
        const float hn0 = fasttanh(cn0) * fastsig(acc0[3]);
        c0 = msk ? cn0 : c0;
        const float h20 = msk ? hn0 : hp0; hp0 = h20;
        const float cn1 = c1 * fastsig(acc1[2] + 1.0f) + fastsig(acc1[0]) * fasttanh(acc1[1]);
        const float hn1 = fasttanh(cn1) * fastsig(acc1[3]);
        c1 = msk ? cn1 : c1;
        const float h21 = msk ? hn1 : hp1; hp1 = h21;

        // (F) pack 4 hc per tile into u64; quad0 stores tile0, quad1 stores tile1.
        // Then per-WAVE ack + flag store: no __syncthreads in the loop.
        const unsigned hv0 = f2bf(h20), hv1 = f2bf(h21);
        const int a0 = __shfl((int)hv0, l15, 64),      a1 = __shfl((int)hv0, l15 + 16, 64);
        const int a2 = __shfl((int)hv0, l15 + 32, 64), a3 = __shfl((int)hv0, l15 + 48, 64);
        const int b0 = __shfl((int)hv1, l15, 64),      b1 = __shfl((int)hv1, l15 + 16, 64);
        const int b2 = __shfl((int)hv1, l15 + 32, 64), b3 = __shfl((int)hv1, l15 + 48, 64);
        unsigned short* dstBase = h_all + (size_t)(t + 1) * (B_ * H_) + (size_t)bE * H_
                                + blk * 16 + mpair * 8;
        if (quad == 0){
            const u64 pk = (u64)(unsigned short)a0 | ((u64)(unsigned short)a1 << 16)
                         | ((u64)(unsigned short)a2 << 32) | ((u64)(unsigned short)a3 << 48);
            store8_dev(dstBase, pk);
        } else if (quad == 1){
            const u64 pk = (u64)(unsigned short)b0 | ((u64)(unsigned short)b1 << 16)
                         | ((u64)(unsigned short)b2 << 32) | ((u64)(unsigned short)b3 << 48);
            store8_dev(dstBase + 4, pk);
        }
        wait_vm0();                      // this wave's h stores ack'd at the MALL
        if (lane == 0)
            store4_dev(&flags[blk * 4 + wv], (unsigned)(t + 1));

        // pre-issue next step's 2 flag loads: MALL RT overlaps the tail below
        if (t + 1 < T_){
            pv0 = load4_dev_nowait(flags + lane);
            pv1 = load4_dev_nowait(flags + lane + 64);
        }

        // (G) tail (in notify slack): 16 MFMA on prefetched bf16 x-row
        if (t + 1 < T_){
            accX0 = (v4f){ bias0[0], bias0[1], bias0[2], bias0[3] };
            accX1 = (v4f){ bias1[0], bias1[1], bias1[2], bias1[3] };
#pragma unroll
            for (int kc = 0; kc < 8; ++kc){
                accX0 = __builtin_amdgcn_mfma_f32_16x16x32_bf16(AW0[kc], xe[kc], accX0, 0, 0, 0);
                accX1 = __builtin_amdgcn_mfma_f32_16x16x32_bf16(AW1[kc], xe[kc], accX1, 0, 0, 0);
            }
        }
        qnext = qnext2;
    }
}

// ---------------------------------------------------------------- projection + relu + log-softmax + xent
__global__ void __launch_bounds__(256) loss_kernel(
    const int* __restrict__ a, const int* __restrict__ lengths,
    const float* __restrict__ projB,
    const unsigned short* __restrict__ h_all,
    const unsigned short* __restrict__ Wt,
    float* __restrict__ out)
{
    const int tid = threadIdx.x;
    const int wv = tid >> 6, lane = tid & 63;
    const int l15 = lane & 15, quad = lane >> 4;
    const int wgid = blockIdx.x * 4 + wv;            // 0..1023
    const int row0 = wgid * 16;

    const int rowA = row0 + l15;
    const int bA = rowA >> 9, tA = rowA & 511;
    const unsigned short* hrow = h_all + ((size_t)(tA + 1) * B_ + bA) * H_;

    v4f acc[4] = { {0,0,0,0}, {0,0,0,0}, {0,0,0,0}, {0,0,0,0} };
#pragma unroll
    for (int kc = 0; kc < 16; ++kc){
        const short8 af = *(const short8*)(hrow + kc * 32 + quad * 8);
#pragma unroll
        for (int ntl = 0; ntl < 4; ++ntl){
            const short8 bf = *(const short8*)(Wt + (size_t)(ntl * 16 + l15) * H_ + kc * 32 + quad * 8);
            acc[ntl] = __builtin_amdgcn_mfma_f32_16x16x32_bf16(af, bf, acc[ntl], 0, 0, 0);
        }
    }

    float pb[4]; bool cv[4];
#pragma unroll
    for (int ntl = 0; ntl < 4; ++ntl){
        const int c = ntl * 16 + l15;
        cv[ntl] = (c < L_);
        pb[ntl] = cv[ntl] ? projB[c] : 0.f;
    }

#pragma unroll
    for (int r = 0; r < 4; ++r){
        const int row = row0 + quad * 4 + r;
        const int b = row >> 9, t = row & 511;
        const int len = lengths[b];
        const bool valid = (t < len);

        float lv[4];
#pragma unroll
        for (int ntl = 0; ntl < 4; ++ntl)
            lv[ntl] = fmaxf(acc[ntl][r] + pb[ntl], 0.f);   // relu(logits)

        float mx = -1e30f;
#pragma unroll
        for (int ntl = 0; ntl < 4; ++ntl) if (cv[ntl]) mx = fmaxf(mx, lv[ntl]);
        mx = qredmax(mx);
        float se = 0.f;
#pragma unroll
        for (int ntl = 0; ntl < 4; ++ntl) if (cv[ntl]) se += expf(lv[ntl] - mx);
        se = qredsum(se);
        const int lbl = a[row];
        float cand = 0.f;
#pragma unroll
        for (int ntl = 0; ntl < 4; ++ntl) if (ntl * 16 + l15 == lbl) cand = lv[ntl];
        const float llbl = qredsum(cand);

        if (valid && l15 == 0){
            const float xent = logf(se) + mx - llbl;      // -log_softmax[label]
            atomicAdd(out, xent / ((float)len * 32.0f));
        }
    }
}

// ---------------------------------------------------------------- launch
extern "C" void kernel_launch(void* const* d_in, const int* in_sizes, int n_in,
                              void* d_out, int out_size, void* d_ws, size_t ws_size,
                              hipStream_t stream)
{
    const int*   q   = (const int*)d_in[0];
    const int*   a   = (const int*)d_in[1];
    const int*   len = (const int*)d_in[2];
    const float* we  = (const float*)d_in[3];
    const float* lW  = (const float*)d_in[4];
    const float* lB  = (const float*)d_in[5];
    const float* pW  = (const float*)d_in[6];
    const float* pB  = (const float*)d_in[7];
    float* out = (float*)d_out;

    unsigned char* ws = (unsigned char*)d_ws;
    unsigned int*   setup = (unsigned int*)ws;                       // 4 KiB (reserved)
    unsigned int*   flags = (unsigned int*)(ws + 4096);              // 128 dwords (4 KiB reserved)
    unsigned short* h_all = (unsigned short*)(ws + 8192);            // 513*32*512*2 B = 16.84 MB
    unsigned short* Wt    = (unsigned short*)(ws + 8192 + (size_t)(T_ + 1) * B_ * H_ * 2);  // 64 KiB
    unsigned short* we_bf = (unsigned short*)(ws + 8192 + (size_t)(T_ + 1) * B_ * H_ * 2 + 65536); // 25.6 MB

    init_kernel<<<dim3(6400), dim3(256), 0, stream>>>(pW, we, out, setup, flags, h_all, Wt, we_bf);

    {
        const int* q_ = q; const int* len_ = len; const unsigned short* we_ = we_bf;
        const float* lW_ = lW; const float* lB_ = lB;
        unsigned short* h_ = h_all; unsigned int* f_ = flags;
        void* args[] = { (void*)&q_, (void*)&len_, (void*)&we_, (void*)&lW_,
                         (void*)&lB_, (void*)&h_, (void*)&f_ };
        hipLaunchCooperativeKernel((void*)lstm_kernel, dim3(NGRID), dim3(256),
                                   args, 0, stream);
    }

    loss_kernel<<<dim3(256), dim3(256), 0, stream>>>(a, len, pB, h_all, Wt, out);
}

// Round 11
// 3313.547 us; speedup vs baseline: 1.0872x; 1.0872x over previous
//
#include <hip/hip_runtime.h>
#include <hip/hip_bf16.h>

#define B_ 32
#define T_ 512
#define E_ 256
#define H_ 512
#define L_ 50
#define V_ 50000
#define NBLK 32          // worker blocks (placement-independent protocol)
#define NGRID 32         // exactly the workers

typedef __attribute__((ext_vector_type(8))) short short8;
typedef __attribute__((ext_vector_type(4))) float v4f;
typedef __attribute__((ext_vector_type(4))) int i4;
typedef unsigned long long u64;

__device__ __forceinline__ unsigned short f2bf(float f){
    union { float f; unsigned u; } v; v.f = f;
    unsigned u = v.u;
    u += 0x7fffu + ((u >> 16) & 1u);   // RNE
    return (unsigned short)(u >> 16);
}
// native-transcendental activations: v_exp_f32 + v_rcp_f32 (~1e-6 rel err, far
// below the bf16 rounding already in the h pipeline; validated absmax=0 r2-r10)
__device__ __forceinline__ float fastsig(float x){
    return __builtin_amdgcn_rcpf(1.0f + __expf(-x));
}
__device__ __forceinline__ float fasttanh(float x){
    return 1.0f - 2.0f * __builtin_amdgcn_rcpf(__expf(2.0f * x) + 1.0f);
}

__device__ __forceinline__ float qredmax(float v){
    v = fmaxf(v, __shfl_xor(v, 1, 64));
    v = fmaxf(v, __shfl_xor(v, 2, 64));
    v = fmaxf(v, __shfl_xor(v, 4, 64));
    v = fmaxf(v, __shfl_xor(v, 8, 64));
    return v;
}
__device__ __forceinline__ float qredsum(float v){
    v += __shfl_xor(v, 1, 64);
    v += __shfl_xor(v, 2, 64);
    v += __shfl_xor(v, 4, 64);
    v += __shfl_xor(v, 8, 64);
    return v;
}

// DEVICE-coherent memory ops: sc0 sc1 = bypass L1 AND L2, coherence point is
// the MALL. Placement-independent (r9-proven).
__device__ __forceinline__ i4 load16_dev(const void* p){
    i4 r;
    asm volatile("global_load_dwordx4 %0, %1, off sc0 sc1" : "=v"(r) : "v"(p) : "memory");
    return r;
}
__device__ __forceinline__ void store8_dev(void* p, u64 v){
    asm volatile("global_store_dwordx2 %0, %1, off sc0 sc1" : : "v"(p), "v"(v) : "memory");
}
__device__ __forceinline__ void wait_vm0(){
    asm volatile("s_waitcnt vmcnt(0)" ::: "memory");
}

// ---------------------------------------------------------------- init + we->bf16 convert + h canary fill
// grid 6400 x 256 = 1,638,400 threads.
// h_all[1..T] is pre-filled with 0xFFFF (bf16 -NaN) — a bit pattern that
// tanh*sig outputs can NEVER produce through f2bf. Consumers validate h
// chunks directly against this canary: the h data is self-flagging, so the
// recurrence needs NO flags, NO store-ack, NO __syncthreads.
__global__ void init_kernel(const float* __restrict__ projW,
                            const float* __restrict__ we,
                            float* __restrict__ out,
                            unsigned short* __restrict__ h_all,
                            unsigned short* __restrict__ Wt,
                            unsigned short* __restrict__ we_bf)
{
    const int i = blockIdx.x * 256 + threadIdx.x;
    if (i == 0) out[0] = 0.f;
    if (i < B_ * H_) h_all[i] = 0;                  // h step 0 = zeros (real data)
    if (i < (T_ * B_ * H_) / 8){                    // canary fill steps 1..T
        const short8 can = { (short)0xFFFF,(short)0xFFFF,(short)0xFFFF,(short)0xFFFF,
                             (short)0xFFFF,(short)0xFFFF,(short)0xFFFF,(short)0xFFFF };
        *(short8*)(h_all + (size_t)B_ * H_ + (size_t)i * 8) = can;
    }
    if (i < 64 * H_){                               // Wt[c][k] = proj_W[k][c], bf16, pad c>=50 with 0
        const int c = i >> 9;
        const int k = i & 511;
        const float v = (c < L_) ? projW[k * L_ + c] : 0.f;
        Wt[i] = f2bf(v);
    }
    if (i < (V_ * E_) / 8){                         // bf16 embedding table (same RNE as before)
        const v4f* src = (const v4f*)(we + (size_t)i * 8);
        const v4f a = src[0], b = src[1];
        short8 o;
#pragma unroll
        for (int j = 0; j < 4; ++j){ o[j] = (short)f2bf(a[j]); o[4 + j] = (short)f2bf(b[j]); }
        *(short8*)(we_bf + (size_t)i * 8) = o;
    }
}

// ---------------------------------------------------------------- LSTM recurrence (cooperative, canary-validated)
// r9 base (placement-robust sc0 sc1), with the ENTIRE flag protocol replaced
// by canary validation (r10 post-mortem: flag poll + store-ack were 2 of the
// 3 serialized MALL RTs per step; the pre-issue attempt added an RT instead
// of removing one because blocks run in lockstep):
//  * consumer loads h[t] chunks (sc0 sc1, MALL-fresh) and validates
//    "no 16-bit element == 0xFFFF" via a v_pk_max_u16 tree (~150cy);
//    retries until all canaries are overwritten. The first attempt usually
//    succeeds -> ONE MALL RT per step total.
//  * producer just stores h (fire-and-forget): no ack wait, no flag store,
//    no __syncthreads. Skew is bounded at 1 step (per-t buffers).
//  * 8B-store granularity means a chunk can be half-written; the per-chunk
//    canary check handles tearing (retry until both halves present).
__global__ void __launch_bounds__(256, 1) lstm_kernel(
    const int* __restrict__ q, const int* __restrict__ lengths,
    const unsigned short* __restrict__ we_bf, const float* __restrict__ lstmW,
    const float* __restrict__ lstmB,
    unsigned short* __restrict__ h_all)
{
    const int tid  = threadIdx.x;
    const int blk  = blockIdx.x;     // worker slot 0..31

    const int wv   = tid >> 6;       // 0..3
    const int lane = tid & 63;
    const int nt = wv & 1, mpair = wv >> 1;   // n-half, m-tile pair
    const int l15 = lane & 15, quad = lane >> 4;

    // ---- A-operand mapping (lane&15 = m = z-col in tile; k = quad*8 + j)
    const int hcA0 = blk * 16 + (mpair * 2 + 0) * 4 + (l15 >> 2);
    const int hcA1 = blk * 16 + (mpair * 2 + 1) * 4 + (l15 >> 2);
    const int gA   = l15 & 3;
    const int colA0 = gA * H_ + hcA0;
    const int colA1 = gA * H_ + hcA1;

    short8 AW0[8], AW1[8], AH0[16], AH1[16];
#pragma unroll
    for (int kc = 0; kc < 8; ++kc){     // x-part rows 0..255
        short8 f0, f1;
#pragma unroll
        for (int j = 0; j < 8; ++j){
            const int r = kc * 32 + quad * 8 + j;
            f0[j] = (short)f2bf(lstmW[(size_t)r * 2048 + colA0]);
            f1[j] = (short)f2bf(lstmW[(size_t)r * 2048 + colA1]);
        }
        AW0[kc] = f0; AW1[kc] = f1;
    }
#pragma unroll
    for (int kc = 0; kc < 16; ++kc){    // h-part rows 256..767
        short8 f0, f1;
#pragma unroll
        for (int j = 0; j < 8; ++j){
            const int r = E_ + kc * 32 + quad * 8 + j;
            f0[j] = (short)f2bf(lstmW[(size_t)r * 2048 + colA0]);
            f1[j] = (short)f2bf(lstmW[(size_t)r * 2048 + colA1]);
        }
        AH0[kc] = f0; AH1[kc] = f1;
    }

    // ---- epilogue mapping (lane&15 = n = batch; D row quad*4+reg -> hc=quad, gate=reg)
    const int bE   = nt * 16 + l15;
    const int hcE0 = blk * 16 + (mpair * 2 + 0) * 4 + quad;
    const int hcE1 = blk * 16 + (mpair * 2 + 1) * 4 + quad;
    float bias0[4], bias1[4];
#pragma unroll
    for (int g = 0; g < 4; ++g){ bias0[g] = lstmB[g * H_ + hcE0]; bias1[g] = lstmB[g * H_ + hcE1]; }
    const int lenb = lengths[bE];

    float c0 = 0.f, c1 = 0.f, hp0 = 0.f, hp1 = 0.f;

    // pre-loop x-part for t=0 (cold path)
    v4f accX0 = { bias0[0], bias0[1], bias0[2], bias0[3] };
    v4f accX1 = { bias1[0], bias1[1], bias1[2], bias1[3] };
    {
        const int qv = q[bE * T_];
        const short8* wp = (const short8*)(we_bf + (size_t)qv * E_);
#pragma unroll
        for (int kc = 0; kc < 8; ++kc){
            const short8 eb = wp[kc * 4 + quad];
            accX0 = __builtin_amdgcn_mfma_f32_16x16x32_bf16(AW0[kc], eb, accX0, 0, 0, 0);
            accX1 = __builtin_amdgcn_mfma_f32_16x16x32_bf16(AW1[kc], eb, accX1, 0, 0, 0);
        }
    }

    int qnext = q[bE * T_ + 1];      // q for t+1 (prefetched one iter ahead)

    for (int t = 0; t < T_; ++t){
        // (C) canary-validated h load: loads ARE the synchronization.
        const unsigned short* hrow = h_all + (size_t)t * (B_ * H_) + (size_t)bE * H_;
        i4 hbuf[16];
        {
            int guard = 0;
            for (;;){
#pragma unroll
                for (int kc = 0; kc < 16; ++kc)
                    hbuf[kc] = load16_dev(hrow + kc * 32 + quad * 8);
                wait_vm0();          // also drains our previous h stores
                unsigned m0 = 0u, m1 = 0u, m2 = 0u, m3 = 0u;
#pragma unroll
                for (int kc = 0; kc < 16; ++kc){
                    asm("v_pk_max_u16 %0, %0, %1" : "+v"(m0) : "v"(hbuf[kc][0]));
                    asm("v_pk_max_u16 %0, %0, %1" : "+v"(m1) : "v"(hbuf[kc][1]));
                    asm("v_pk_max_u16 %0, %0, %1" : "+v"(m2) : "v"(hbuf[kc][2]));
                    asm("v_pk_max_u16 %0, %0, %1" : "+v"(m3) : "v"(hbuf[kc][3]));
                }
                asm("v_pk_max_u16 %0, %0, %1" : "+v"(m0) : "v"(m1));
                asm("v_pk_max_u16 %0, %0, %1" : "+v"(m2) : "v"(m3));
                asm("v_pk_max_u16 %0, %0, %1" : "+v"(m0) : "v"(m2));
                const bool valid = ((m0 & 0xFFFFu) != 0xFFFFu) && ((m0 >> 16) != 0xFFFFu);
                if (__ballot(valid) == 0xFFFFFFFFFFFFFFFFull) break;
                if (++guard > (1 << 14)) break;   // safety valve (absmax-visible if hit)
            }
        }

        // (A) issue bf16 x-row loads for t+1 NOW (plain cached loads): RT
        // hides under the 32 MFMA + gates below.
        short8 xe[8];
        {
            const short8* wp = (const short8*)(we_bf + (size_t)qnext * E_);
#pragma unroll
            for (int kc = 0; kc < 8; ++kc) xe[kc] = wp[kc * 4 + quad];
        }
        const int qnext2 = q[bE * T_ + ((t + 2 < T_) ? (t + 2) : (T_ - 1))];

        // (D) 32 MFMA in 4 independent chains (kc even/odd x 2 tiles)
        v4f a0e = accX0, a1e = accX1;
        v4f a0o = { 0.f, 0.f, 0.f, 0.f }, a1o = { 0.f, 0.f, 0.f, 0.f };
#pragma unroll
        for (int kc = 0; kc < 16; kc += 2){
            union { i4 i; short8 s; } cv0, cv1; cv0.i = hbuf[kc]; cv1.i = hbuf[kc + 1];
            a0e = __builtin_amdgcn_mfma_f32_16x16x32_bf16(AH0[kc],     cv0.s, a0e, 0, 0, 0);
            a1e = __builtin_amdgcn_mfma_f32_16x16x32_bf16(AH1[kc],     cv0.s, a1e, 0, 0, 0);
            a0o = __builtin_amdgcn_mfma_f32_16x16x32_bf16(AH0[kc + 1], cv1.s, a0o, 0, 0, 0);
            a1o = __builtin_amdgcn_mfma_f32_16x16x32_bf16(AH1[kc + 1], cv1.s, a1o, 0, 0, 0);
        }
        const v4f acc0 = a0e + a0o;
        const v4f acc1 = a1e + a1o;

        // (E) gates per tile: i,j,f,o = acc[0..3]; native exp/rcp
        const bool msk = (t < lenb);
        const float cn0 = c0 * fastsig(acc0[2] + 1.0f) + fastsig(acc0[0]) * fasttanh(acc0[1]);
        const float hn0 = fasttanh(cn0) * fastsig(acc0[3]);
        c0 = msk ? cn0 : c0;
        const float h20 = msk ? hn0 : hp0; hp0 = h20;
        const float cn1 = c1 * fastsig(acc1[2] + 1.0f) + fastsig(acc1[0]) * fasttanh(acc1[1]);
        const float hn1 = fasttanh(cn1) * fastsig(acc1[3]);
        c1 = msk ? cn1 : c1;
        const float h21 = msk ? hn1 : hp1; hp1 = h21;

        // (F) pack 4 hc per tile into u64; quad0 stores tile0, quad1 stores
        // tile1. Fire-and-forget: consumers validate, no ack/flag/sync needed.
        const unsigned hv0 = f2bf(h20), hv1 = f2bf(h21);
        const int a0 = __shfl((int)hv0, l15, 64),      a1 = __shfl((int)hv0, l15 + 16, 64);
        const int a2 = __shfl((int)hv0, l15 + 32, 64), a3 = __shfl((int)hv0, l15 + 48, 64);
        const int b0 = __shfl((int)hv1, l15, 64),      b1 = __shfl((int)hv1, l15 + 16, 64);
        const int b2 = __shfl((int)hv1, l15 + 32, 64), b3 = __shfl((int)hv1, l15 + 48, 64);
        unsigned short* dstBase = h_all + (size_t)(t + 1) * (B_ * H_) + (size_t)bE * H_
                                + blk * 16 + mpair * 8;
        if (quad == 0){
            const u64 pk = (u64)(unsigned short)a0 | ((u64)(unsigned short)a1 << 16)
                         | ((u64)(unsigned short)a2 << 32) | ((u64)(unsigned short)a3 << 48);
            store8_dev(dstBase, pk);
        } else if (quad == 1){
            const u64 pk = (u64)(unsigned short)b0 | ((u64)(unsigned short)b1 << 16)
                         | ((u64)(unsigned short)b2 << 32) | ((u64)(unsigned short)b3 << 48);
            store8_dev(dstBase + 4, pk);
        }

        // (G) tail: 16 MFMA on prefetched bf16 x-row (no waits in between)
        if (t + 1 < T_){
            accX0 = (v4f){ bias0[0], bias0[1], bias0[2], bias0[3] };
            accX1 = (v4f){ bias1[0], bias1[1], bias1[2], bias1[3] };
#pragma unroll
            for (int kc = 0; kc < 8; ++kc){
                accX0 = __builtin_amdgcn_mfma_f32_16x16x32_bf16(AW0[kc], xe[kc], accX0, 0, 0, 0);
                accX1 = __builtin_amdgcn_mfma_f32_16x16x32_bf16(AW1[kc], xe[kc], accX1, 0, 0, 0);
            }
        }
        qnext = qnext2;
    }
}

// ---------------------------------------------------------------- projection + relu + log-softmax + xent
// h reads via sc0 sc1 (preloaded, one wait): lstm stored h bypassing L2, and
// init cached canary lines — plain loads could hit stale canary in an L2 that
// isn't invalidated at dispatch. MALL reads are unconditionally correct.
__global__ void __launch_bounds__(256) loss_kernel(
    const int* __restrict__ a, const int* __restrict__ lengths,
    const float* __restrict__ projB,
    const unsigned short* __restrict__ h_all,
    const unsigned short* __restrict__ Wt,
    float* __restrict__ out)
{
    const int tid = threadIdx.x;
    const int wv = tid >> 6, lane = tid & 63;
    const int l15 = lane & 15, quad = lane >> 4;
    const int wgid = blockIdx.x * 4 + wv;            // 0..1023
    const int row0 = wgid * 16;

    const int rowA = row0 + l15;
    const int bA = rowA >> 9, tA = rowA & 511;
    const unsigned short* hrow = h_all + ((size_t)(tA + 1) * B_ + bA) * H_;

    i4 afb[16];
#pragma unroll
    for (int kc = 0; kc < 16; ++kc)
        afb[kc] = load16_dev(hrow + kc * 32 + quad * 8);
    wait_vm0();

    v4f acc[4] = { {0,0,0,0}, {0,0,0,0}, {0,0,0,0}, {0,0,0,0} };
#pragma unroll
    for (int kc = 0; kc < 16; ++kc){
        union { i4 i; short8 s; } u; u.i = afb[kc];
#pragma unroll
        for (int ntl = 0; ntl < 4; ++ntl){
            const short8 bf = *(const short8*)(Wt + (size_t)(ntl * 16 + l15) * H_ + kc * 32 + quad * 8);
            acc[ntl] = __builtin_amdgcn_mfma_f32_16x16x32_bf16(u.s, bf, acc[ntl], 0, 0, 0);
        }
    }

    float pb[4]; bool cv[4];
#pragma unroll
    for (int ntl = 0; ntl < 4; ++ntl){
        const int c = ntl * 16 + l15;
        cv[ntl] = (c < L_);
        pb[ntl] = cv[ntl] ? projB[c] : 0.f;
    }

#pragma unroll
    for (int r = 0; r < 4; ++r){
        const int row = row0 + quad * 4 + r;
        const int b = row >> 9, t = row & 511;
        const int len = lengths[b];
        const bool valid = (t < len);

        float lv[4];
#pragma unroll
        for (int ntl = 0; ntl < 4; ++ntl)
            lv[ntl] = fmaxf(acc[ntl][r] + pb[ntl], 0.f);   // relu(logits)

        float mx = -1e30f;
#pragma unroll
        for (int ntl = 0; ntl < 4; ++ntl) if (cv[ntl]) mx = fmaxf(mx, lv[ntl]);
        mx = qredmax(mx);
        float se = 0.f;
#pragma unroll
        for (int ntl = 0; ntl < 4; ++ntl) if (cv[ntl]) se += expf(lv[ntl] - mx);
        se = qredsum(se);
        const int lbl = a[row];
        float cand = 0.f;
#pragma unroll
        for (int ntl = 0; ntl < 4; ++ntl) if (ntl * 16 + l15 == lbl) cand = lv[ntl];
        const float llbl = qredsum(cand);

        if (valid && l15 == 0){
            const float xent = logf(se) + mx - llbl;      // -log_softmax[label]
            atomicAdd(out, xent / ((float)len * 32.0f));
        }
    }
}

// ---------------------------------------------------------------- launch
extern "C" void kernel_launch(void* const* d_in, const int* in_sizes, int n_in,
                              void* d_out, int out_size, void* d_ws, size_t ws_size,
                              hipStream_t stream)
{
    const int*   q   = (const int*)d_in[0];
    const int*   a   = (const int*)d_in[1];
    const int*   len = (const int*)d_in[2];
    const float* we  = (const float*)d_in[3];
    const float* lW  = (const float*)d_in[4];
    const float* lB  = (const float*)d_in[5];
    const float* pW  = (const float*)d_in[6];
    const float* pB  = (const float*)d_in[7];
    float* out = (float*)d_out;

    unsigned char* ws = (unsigned char*)d_ws;
    unsigned short* h_all = (unsigned short*)(ws + 8192);            // 513*32*512*2 B = 16.84 MB
    unsigned short* Wt    = (unsigned short*)(ws + 8192 + (size_t)(T_ + 1) * B_ * H_ * 2);  // 64 KiB
    unsigned short* we_bf = (unsigned short*)(ws + 8192 + (size_t)(T_ + 1) * B_ * H_ * 2 + 65536); // 25.6 MB

    init_kernel<<<dim3(6400), dim3(256), 0, stream>>>(pW, we, out, h_all, Wt, we_bf);

    {
        const int* q_ = q; const int* len_ = len; const unsigned short* we_ = we_bf;
        const float* lW_ = lW; const float* lB_ = lB;
        unsigned short* h_ = h_all;
        void* args[] = { (void*)&q_, (void*)&len_, (void*)&we_, (void*)&lW_,
                         (void*)&lB_, (void*)&h_ };
        hipLaunchCooperativeKernel((void*)lstm_kernel, dim3(NGRID), dim3(256),
                                   args, 0, stream);
    }

    loss_kernel<<<dim3(256), dim3(256), 0, stream>>>(a, len, pB, h_all, Wt, out);
}

// Round 12
// 2420.898 us; speedup vs baseline: 1.4881x; 1.3687x over previous
//
#include <hip/hip_runtime.h>
#include <hip/hip_bf16.h>

#define B_ 32
#define T_ 512
#define E_ 256
#define H_ 512
#define L_ 50
#define V_ 50000
#define NBLK 32          // worker blocks (placement-independent protocol)
#define NGRID 256        // 32 workers + 224 clock-boost spinners

typedef __attribute__((ext_vector_type(8))) short short8;
typedef __attribute__((ext_vector_type(4))) float v4f;
typedef __attribute__((ext_vector_type(4))) int i4;
typedef unsigned long long u64;

__device__ __forceinline__ unsigned short f2bf(float f){
    union { float f; unsigned u; } v; v.f = f;
    unsigned u = v.u;
    u += 0x7fffu + ((u >> 16) & 1u);   // RNE
    return (unsigned short)(u >> 16);
}
// native-transcendental activations: v_exp_f32 + v_rcp_f32 (~1e-6 rel err, far
// below the bf16 rounding already in the h pipeline; validated absmax=0 r2-r11)
__device__ __forceinline__ float fastsig(float x){
    return __builtin_amdgcn_rcpf(1.0f + __expf(-x));
}
__device__ __forceinline__ float fasttanh(float x){
    return 1.0f - 2.0f * __builtin_amdgcn_rcpf(__expf(2.0f * x) + 1.0f);
}

__device__ __forceinline__ float qredmax(float v){
    v = fmaxf(v, __shfl_xor(v, 1, 64));
    v = fmaxf(v, __shfl_xor(v, 2, 64));
    v = fmaxf(v, __shfl_xor(v, 4, 64));
    v = fmaxf(v, __shfl_xor(v, 8, 64));
    return v;
}
__device__ __forceinline__ float qredsum(float v){
    v += __shfl_xor(v, 1, 64);
    v += __shfl_xor(v, 2, 64);
    v += __shfl_xor(v, 4, 64);
    v += __shfl_xor(v, 8, 64);
    return v;
}

// DEVICE-coherent memory ops: sc0 sc1 = bypass L1 AND L2, coherence point is
// the MALL. Placement-independent (r9-proven: 2425us, absmax 0, any node).
__device__ __forceinline__ i4 load16_dev(const void* p){
    i4 r;
    asm volatile("global_load_dwordx4 %0, %1, off sc0 sc1" : "=v"(r) : "v"(p) : "memory");
    return r;
}
__device__ __forceinline__ void store8_dev(void* p, u64 v){
    asm volatile("global_store_dwordx2 %0, %1, off sc0 sc1" : : "v"(p), "v"(v) : "memory");
}
__device__ __forceinline__ void store4_dev(void* p, unsigned v){
    asm volatile("global_store_dword %0, %1, off sc0 sc1" : : "v"(p), "v"(v) : "memory");
}
__device__ __forceinline__ unsigned load4_dev_wait(const void* p){
    unsigned r;
    asm volatile("global_load_dword %0, %1, off sc0 sc1\n\ts_waitcnt vmcnt(0)"
                 : "=v"(r) : "v"(p) : "memory");
    return r;
}
__device__ __forceinline__ void wait_vm0(){
    asm volatile("s_waitcnt vmcnt(0)" ::: "memory");
}

// ---------------------------------------------------------------- init + we->bf16 convert
// grid 6400 x 256 = 1,638,400 threads; each converts 8 floats of word_embed.
__global__ void init_kernel(const float* __restrict__ projW,
                            const float* __restrict__ we,
                            float* __restrict__ out,
                            unsigned int* __restrict__ setup,   // reserved
                            unsigned int* __restrict__ flags,   // [0..31] step tags, [64] done
                            unsigned short* __restrict__ h0,
                            unsigned short* __restrict__ Wt,
                            unsigned short* __restrict__ we_bf)
{
    const int i = blockIdx.x * 256 + threadIdx.x;
    if (i < 1024) setup[i] = 0u;
    if (i < 128) flags[i] = 0u;                     // step tags + done word
    if (i == 0) out[0] = 0.f;
    if (i < B_ * H_) h0[i] = 0;                     // h_all step 0 = zeros
    if (i < 64 * H_){                               // Wt[c][k] = proj_W[k][c], bf16, pad c>=50 with 0
        const int c = i >> 9;
        const int k = i & 511;
        const float v = (c < L_) ? projW[k * L_ + c] : 0.f;
        Wt[i] = f2bf(v);
    }
    if (i < (V_ * E_) / 8){                         // bf16 embedding table (same RNE as before)
        const v4f* src = (const v4f*)(we + (size_t)i * 8);
        const v4f a = src[0], b = src[1];
        short8 o;
#pragma unroll
        for (int j = 0; j < 4; ++j){ o[j] = (short)f2bf(a[j]); o[4 + j] = (short)f2bf(b[j]); }
        *(short8*)(we_bf + (size_t)i * 8) = o;
    }
}

// ---------------------------------------------------------------- LSTM recurrence (cooperative, device-coherent)
// Worker protocol is byte-identical to R9 (proven 2425us, placement-robust):
// monotonic dword block flags @ MALL, lane<32 sleep-poll, u64 shuffle-packed
// h stores, vmcnt0 ack + __syncthreads + single flag store; xe issued after
// the h-wait (RT hides under MFMA+gates).
// Round-12 delta: CLOCK-BOOST SPINNERS. Blocks 32..255 run dense independent
// VALU FMAs (~75% issue busy) until workers set flags[64] (sc1, MALL —
// visibility proven by r9's protocol). Two independent cycle-accountings put
// the active clock at ~0.65-0.7GHz (idle-chip DPM); busying the other 224 CUs
// should raise it toward 2.4GHz, shrinking every RT/compute term ~3x.
// r11 post-mortem (canary, FETCH 256MB, retries): reverted to R9 base.
__global__ void __launch_bounds__(256, 1) lstm_kernel(
    const int* __restrict__ q, const int* __restrict__ lengths,
    const unsigned short* __restrict__ we_bf, const float* __restrict__ lstmW,
    const float* __restrict__ lstmB,
    unsigned short* __restrict__ h_all, unsigned int* __restrict__ flags)
{
    const int tid  = threadIdx.x;
    const int blk  = blockIdx.x;

    if (blk >= NBLK){
        // ---- clock-boost spinner: 4 independent FMA chains; poll done word
        // (sc1, MALL-fresh) every 32 iters; hard cap ~7ms.
        float a0 = 1.0f + (float)tid, a1 = 2.0f, a2 = 3.0f, a3 = 4.0f;
        const unsigned int* dp = flags + 64;
        int done = 0;
        for (int it = 0; it < (1 << 18) && !done; ++it){
#pragma unroll
            for (int j = 0; j < 16; ++j){
                a0 = __builtin_fmaf(a0, 0.9999999f, 1e-7f);
                a1 = __builtin_fmaf(a1, 0.9999999f, 1e-7f);
                a2 = __builtin_fmaf(a2, 0.9999999f, 1e-7f);
                a3 = __builtin_fmaf(a3, 0.9999999f, 1e-7f);
            }
            if ((it & 31) == 0)
                done = (load4_dev_wait(dp) != 0u);
        }
        asm volatile("" :: "v"(a0), "v"(a1), "v"(a2), "v"(a3));
        return;
    }

    const int wv   = tid >> 6;       // 0..3
    const int lane = tid & 63;
    const int nt = wv & 1, mpair = wv >> 1;   // n-half, m-tile pair
    const int l15 = lane & 15, quad = lane >> 4;

    // ---- A-operand mapping (lane&15 = m = z-col in tile; k = quad*8 + j)
    const int hcA0 = blk * 16 + (mpair * 2 + 0) * 4 + (l15 >> 2);
    const int hcA1 = blk * 16 + (mpair * 2 + 1) * 4 + (l15 >> 2);
    const int gA   = l15 & 3;
    const int colA0 = gA * H_ + hcA0;
    const int colA1 = gA * H_ + hcA1;

    short8 AW0[8], AW1[8], AH0[16], AH1[16];
#pragma unroll
    for (int kc = 0; kc < 8; ++kc){     // x-part rows 0..255
        short8 f0, f1;
#pragma unroll
        for (int j = 0; j < 8; ++j){
            const int r = kc * 32 + quad * 8 + j;
            f0[j] = (short)f2bf(lstmW[(size_t)r * 2048 + colA0]);
            f1[j] = (short)f2bf(lstmW[(size_t)r * 2048 + colA1]);
        }
        AW0[kc] = f0; AW1[kc] = f1;
    }
#pragma unroll
    for (int kc = 0; kc < 16; ++kc){    // h-part rows 256..767
        short8 f0, f1;
#pragma unroll
        for (int j = 0; j < 8; ++j){
            const int r = E_ + kc * 32 + quad * 8 + j;
            f0[j] = (short)f2bf(lstmW[(size_t)r * 2048 + colA0]);
            f1[j] = (short)f2bf(lstmW[(size_t)r * 2048 + colA1]);
        }
        AH0[kc] = f0; AH1[kc] = f1;
    }

    // ---- epilogue mapping (lane&15 = n = batch; D row quad*4+reg -> hc=quad, gate=reg)
    const int bE   = nt * 16 + l15;
    const int hcE0 = blk * 16 + (mpair * 2 + 0) * 4 + quad;
    const int hcE1 = blk * 16 + (mpair * 2 + 1) * 4 + quad;
    float bias0[4], bias1[4];
#pragma unroll
    for (int g = 0; g < 4; ++g){ bias0[g] = lstmB[g * H_ + hcE0]; bias1[g] = lstmB[g * H_ + hcE1]; }
    const int lenb = lengths[bE];

    float c0 = 0.f, c1 = 0.f, hp0 = 0.f, hp1 = 0.f;

    // pre-loop x-part for t=0 (cold path)
    v4f accX0 = { bias0[0], bias0[1], bias0[2], bias0[3] };
    v4f accX1 = { bias1[0], bias1[1], bias1[2], bias1[3] };
    {
        const int qv = q[bE * T_];
        const short8* wp = (const short8*)(we_bf + (size_t)qv * E_);
#pragma unroll
        for (int kc = 0; kc < 8; ++kc){
            const short8 eb = wp[kc * 4 + quad];
            accX0 = __builtin_amdgcn_mfma_f32_16x16x32_bf16(AW0[kc], eb, accX0, 0, 0, 0);
            accX1 = __builtin_amdgcn_mfma_f32_16x16x32_bf16(AW1[kc], eb, accX1, 0, 0, 0);
        }
    }

    int qnext = q[bE * T_ + 1];      // q for t+1 (prefetched one iter ahead)

    for (int t = 0; t < T_; ++t){
        // (B) poll 32 monotonic producer flags (lanes 0..31): f >= t means
        // h[t] is committed at the MALL by that block.
        if (t > 0){
            int guard = 0;
            for (;;){
                unsigned f = 0xFFFFFFFFu;
                if (lane < NBLK) f = load4_dev_wait(flags + lane);
                if (__ballot(f >= (unsigned)t) == 0xFFFFFFFFFFFFFFFFull) break;
                __builtin_amdgcn_s_sleep(1);
                if (++guard > (1 << 16)) break;   // safety valve (never binding normally)
            }
        }

        // (C) all 16 h B-frag loads from the MALL, ONE wait
        const unsigned short* hrow = h_all + (size_t)t * (B_ * H_) + (size_t)bE * H_;
        i4 hbuf[16];
#pragma unroll
        for (int kc = 0; kc < 16; ++kc)
            hbuf[kc] = load16_dev(hrow + kc * 32 + quad * 8);
        wait_vm0();

        // (A) issue bf16 x-row loads for t+1 NOW (plain cached loads): RT
        // hides under the 32 MFMA + gates below; drained by (F)'s ack wait.
        short8 xe[8];
        {
            const short8* wp = (const short8*)(we_bf + (size_t)qnext * E_);
#pragma unroll
            for (int kc = 0; kc < 8; ++kc) xe[kc] = wp[kc * 4 + quad];
        }
        const int qnext2 = q[bE * T_ + ((t + 2 < T_) ? (t + 2) : (T_ - 1))];

        // (D) 32 MFMA in 4 independent chains (kc even/odd x 2 tiles)
        v4f a0e = accX0, a1e = accX1;
        v4f a0o = { 0.f, 0.f, 0.f, 0.f }, a1o = { 0.f, 0.f, 0.f, 0.f };
#pragma unroll
        for (int kc = 0; kc < 16; kc += 2){
            union { i4 i; short8 s; } cv0, cv1; cv0.i = hbuf[kc]; cv1.i = hbuf[kc + 1];
            a0e = __builtin_amdgcn_mfma_f32_16x16x32_bf16(AH0[kc],     cv0.s, a0e, 0, 0, 0);
            a1e = __builtin_amdgcn_mfma_f32_16x16x32_bf16(AH1[kc],     cv0.s, a1e, 0, 0, 0);
            a0o = __builtin_amdgcn_mfma_f32_16x16x32_bf16(AH0[kc + 1], cv1.s, a0o, 0, 0, 0);
            a1o = __builtin_amdgcn_mfma_f32_16x16x32_bf16(AH1[kc + 1], cv1.s, a1o, 0, 0, 0);
        }
        const v4f acc0 = a0e + a0o;
        const v4f acc1 = a1e + a1o;

        // (E) gates per tile: i,j,f,o = acc[0..3]; native exp/rcp
        const bool msk = (t < lenb);
        const float cn0 = c0 * fastsig(acc0[2] + 1.0f) + fastsig(acc0[0]) * fasttanh(acc0[1]);
        const float hn0 = fasttanh(cn0) * fastsig(acc0[3]);
        c0 = msk ? cn0 : c0;
        const float h20 = msk ? hn0 : hp0; hp0 = h20;
        const float cn1 = c1 * fastsig(acc1[2] + 1.0f) + fastsig(acc1[0]) * fasttanh(acc1[1]);
        const float hn1 = fasttanh(cn1) * fastsig(acc1[3]);
        c1 = msk ? cn1 : c1;
        const float h21 = msk ? hn1 : hp1; hp1 = h21;

        // (F) pack 4 hc per tile into u64; quad0 stores tile0, quad1 stores tile1
        const unsigned hv0 = f2bf(h20), hv1 = f2bf(h21);
        const int a0 = __shfl((int)hv0, l15, 64),      a1 = __shfl((int)hv0, l15 + 16, 64);
        const int a2 = __shfl((int)hv0, l15 + 32, 64), a3 = __shfl((int)hv0, l15 + 48, 64);
        const int b0 = __shfl((int)hv1, l15, 64),      b1 = __shfl((int)hv1, l15 + 16, 64);
        const int b2 = __shfl((int)hv1, l15 + 32, 64), b3 = __shfl((int)hv1, l15 + 48, 64);
        unsigned short* dstBase = h_all + (size_t)(t + 1) * (B_ * H_) + (size_t)bE * H_
                                + blk * 16 + mpair * 8;
        if (quad == 0){
            const u64 pk = (u64)(unsigned short)a0 | ((u64)(unsigned short)a1 << 16)
                         | ((u64)(unsigned short)a2 << 32) | ((u64)(unsigned short)a3 << 48);
            store8_dev(dstBase, pk);
        } else if (quad == 1){
            const u64 pk = (u64)(unsigned short)b0 | ((u64)(unsigned short)b1 << 16)
                         | ((u64)(unsigned short)b2 << 32) | ((u64)(unsigned short)b3 << 48);
            store8_dev(dstBase + 4, pk);
        }
        wait_vm0();                      // h stores ack'd at the MALL (xe long landed)
        __syncthreads();                 // all waves of block done
        if (tid == 0)
            store4_dev(&flags[blk], (unsigned)(t + 1));

        // (G) tail (in notify slack): 16 MFMA on prefetched bf16 x-row
        if (t + 1 < T_){
            accX0 = (v4f){ bias0[0], bias0[1], bias0[2], bias0[3] };
            accX1 = (v4f){ bias1[0], bias1[1], bias1[2], bias1[3] };
#pragma unroll
            for (int kc = 0; kc < 8; ++kc){
                accX0 = __builtin_amdgcn_mfma_f32_16x16x32_bf16(AW0[kc], xe[kc], accX0, 0, 0, 0);
                accX1 = __builtin_amdgcn_mfma_f32_16x16x32_bf16(AW1[kc], xe[kc], accX1, 0, 0, 0);
            }
        }
        qnext = qnext2;
    }

    // signal spinners to exit (MALL store, visible everywhere)
    if (blk == 0 && tid == 0)
        store4_dev(&flags[64], 1u);
}

// ---------------------------------------------------------------- projection + relu + log-softmax + xent
__global__ void __launch_bounds__(256) loss_kernel(
    const int* __restrict__ a, const int* __restrict__ lengths,
    const float* __restrict__ projB,
    const unsigned short* __restrict__ h_all,
    const unsigned short* __restrict__ Wt,
    float* __restrict__ out)
{
    const int tid = threadIdx.x;
    const int wv = tid >> 6, lane = tid & 63;
    const int l15 = lane & 15, quad = lane >> 4;
    const int wgid = blockIdx.x * 4 + wv;            // 0..1023
    const int row0 = wgid * 16;

    const int rowA = row0 + l15;
    const int bA = rowA >> 9, tA = rowA & 511;
    const unsigned short* hrow = h_all + ((size_t)(tA + 1) * B_ + bA) * H_;

    v4f acc[4] = { {0,0,0,0}, {0,0,0,0}, {0,0,0,0}, {0,0,0,0} };
#pragma unroll
    for (int kc = 0; kc < 16; ++kc){
        const short8 af = *(const short8*)(hrow + kc * 32 + quad * 8);
#pragma unroll
        for (int ntl = 0; ntl < 4; ++ntl){
            const short8 bf = *(const short8*)(Wt + (size_t)(ntl * 16 + l15) * H_ + kc * 32 + quad * 8);
            acc[ntl] = __builtin_amdgcn_mfma_f32_16x16x32_bf16(af, bf, acc[ntl], 0, 0, 0);
        }
    }

    float pb[4]; bool cv[4];
#pragma unroll
    for (int ntl = 0; ntl < 4; ++ntl){
        const int c = ntl * 16 + l15;
        cv[ntl] = (c < L_);
        pb[ntl] = cv[ntl] ? projB[c] : 0.f;
    }

#pragma unroll
    for (int r = 0; r < 4; ++r){
        const int row = row0 + quad * 4 + r;
        const int b = row >> 9, t = row & 511;
        const int len = lengths[b];
        const bool valid = (t < len);

        float lv[4];
#pragma unroll
        for (int ntl = 0; ntl < 4; ++ntl)
            lv[ntl] = fmaxf(acc[ntl][r] + pb[ntl], 0.f);   // relu(logits)

        float mx = -1e30f;
#pragma unroll
        for (int ntl = 0; ntl < 4; ++ntl) if (cv[ntl]) mx = fmaxf(mx, lv[ntl]);
        mx = qredmax(mx);
        float se = 0.f;
#pragma unroll
        for (int ntl = 0; ntl < 4; ++ntl) if (cv[ntl]) se += expf(lv[ntl] - mx);
        se = qredsum(se);
        const int lbl = a[row];
        float cand = 0.f;
#pragma unroll
        for (int ntl = 0; ntl < 4; ++ntl) if (ntl * 16 + l15 == lbl) cand = lv[ntl];
        const float llbl = qredsum(cand);

        if (valid && l15 == 0){
            const float xent = logf(se) + mx - llbl;      // -log_softmax[label]
            atomicAdd(out, xent / ((float)len * 32.0f));
        }
    }
}

// ---------------------------------------------------------------- launch
extern "C" void kernel_launch(void* const* d_in, const int* in_sizes, int n_in,
                              void* d_out, int out_size, void* d_ws, size_t ws_size,
                              hipStream_t stream)
{
    const int*   q   = (const int*)d_in[0];
    const int*   a   = (const int*)d_in[1];
    const int*   len = (const int*)d_in[2];
    const float* we  = (const float*)d_in[3];
    const float* lW  = (const float*)d_in[4];
    const float* lB  = (const float*)d_in[5];
    const float* pW  = (const float*)d_in[6];
    const float* pB  = (const float*)d_in[7];
    float* out = (float*)d_out;

    unsigned char* ws = (unsigned char*)d_ws;
    unsigned int*   setup = (unsigned int*)ws;                       // 4 KiB (reserved)
    unsigned int*   flags = (unsigned int*)(ws + 4096);              // [0..31] tags, [64] done
    unsigned short* h_all = (unsigned short*)(ws + 8192);            // 513*32*512*2 B = 16.84 MB
    unsigned short* Wt    = (unsigned short*)(ws + 8192 + (size_t)(T_ + 1) * B_ * H_ * 2);  // 64 KiB
    unsigned short* we_bf = (unsigned short*)(ws + 8192 + (size_t)(T_ + 1) * B_ * H_ * 2 + 65536); // 25.6 MB

    init_kernel<<<dim3(6400), dim3(256), 0, stream>>>(pW, we, out, setup, flags, h_all, Wt, we_bf);

    {
        const int* q_ = q; const int* len_ = len; const unsigned short* we_ = we_bf;
        const float* lW_ = lW; const float* lB_ = lB;
        unsigned short* h_ = h_all; unsigned int* f_ = flags;
        void* args[] = { (void*)&q_, (void*)&len_, (void*)&we_, (void*)&lW_,
                         (void*)&lB_, (void*)&h_, (void*)&f_ };
        hipLaunchCooperativeKernel((void*)lstm_kernel, dim3(NGRID), dim3(256),
                                   args, 0, stream);
    }

    loss_kernel<<<dim3(256), dim3(256), 0, stream>>>(a, len, pB, h_all, Wt, out);
}

// Round 13
// 2397.393 us; speedup vs baseline: 1.5027x; 1.0098x over previous
//
#include <hip/hip_runtime.h>
#include <hip/hip_bf16.h>

#define B_ 32
#define T_ 512
#define E_ 256
#define H_ 512
#define L_ 50
#define V_ 50000
#define NBLK 32          // worker blocks (placement-independent protocol)
#define NGRID 32         // exactly the workers — no spinners (r12: clocks pinned ~0.6GHz)

typedef __attribute__((ext_vector_type(8))) short short8;
typedef __attribute__((ext_vector_type(4))) float v4f;
typedef __attribute__((ext_vector_type(4))) int i4;
typedef unsigned long long u64;

__device__ __forceinline__ unsigned short f2bf(float f){
    union { float f; unsigned u; } v; v.f = f;
    unsigned u = v.u;
    u += 0x7fffu + ((u >> 16) & 1u);   // RNE
    return (unsigned short)(u >> 16);
}
// native-transcendental activations: v_exp_f32 + v_rcp_f32 (~1e-6 rel err, far
// below the bf16 rounding already in the h pipeline; validated absmax=0 r2-r12)
__device__ __forceinline__ float fastsig(float x){
    return __builtin_amdgcn_rcpf(1.0f + __expf(-x));
}
__device__ __forceinline__ float fasttanh(float x){
    return 1.0f - 2.0f * __builtin_amdgcn_rcpf(__expf(2.0f * x) + 1.0f);
}

__device__ __forceinline__ float qredmax(float v){
    v = fmaxf(v, __shfl_xor(v, 1, 64));
    v = fmaxf(v, __shfl_xor(v, 2, 64));
    v = fmaxf(v, __shfl_xor(v, 4, 64));
    v = fmaxf(v, __shfl_xor(v, 8, 64));
    return v;
}
__device__ __forceinline__ float qredsum(float v){
    v += __shfl_xor(v, 1, 64);
    v += __shfl_xor(v, 2, 64);
    v += __shfl_xor(v, 4, 64);
    v += __shfl_xor(v, 8, 64);
    return v;
}

// DEVICE-coherent memory ops: sc0 sc1 = bypass L1 AND L2, coherence point is
// the MALL. Placement-independent (r9-proven).
__device__ __forceinline__ i4 load16_dev(const void* p){
    i4 r;
    asm volatile("global_load_dwordx4 %0, %1, off sc0 sc1" : "=v"(r) : "v"(p) : "memory");
    return r;
}
__device__ __forceinline__ void store8_dev(void* p, u64 v){
    asm volatile("global_store_dwordx2 %0, %1, off sc0 sc1" : : "v"(p), "v"(v) : "memory");
}
__device__ __forceinline__ void wait_vm0(){
    asm volatile("s_waitcnt vmcnt(0)" ::: "memory");
}

// ---------------------------------------------------------------- init + we->bf16 convert + h canary fill
// h_all[1..T] pre-filled with 0xFFFF (bf16 -NaN): a bit pattern tanh*sig
// outputs can NEVER produce via f2bf. The h data is self-flagging -> the
// recurrence needs NO flags, NO store-ack, NO __syncthreads (r11 idea).
// r13 fixes r11's regression: consumers re-load ONLY stale chunks on retry
// (r11 re-fetched the full 16KB/wave payload every retry -> FETCH 256MB,
// MALL congestion, VALUBusy 1.42 -> +900us).
__global__ void init_kernel(const float* __restrict__ projW,
                            const float* __restrict__ we,
                            float* __restrict__ out,
                            unsigned short* __restrict__ h_all,
                            unsigned short* __restrict__ Wt,
                            unsigned short* __restrict__ we_bf)
{
    const int i = blockIdx.x * 256 + threadIdx.x;
    if (i == 0) out[0] = 0.f;
    if (i < B_ * H_) h_all[i] = 0;                  // h step 0 = zeros (real data)
    if (i < (T_ * B_ * H_) / 8){                    // canary fill steps 1..T
        const short8 can = { (short)0xFFFF,(short)0xFFFF,(short)0xFFFF,(short)0xFFFF,
                             (short)0xFFFF,(short)0xFFFF,(short)0xFFFF,(short)0xFFFF };
        *(short8*)(h_all + (size_t)B_ * H_ + (size_t)i * 8) = can;
    }
    if (i < 64 * H_){                               // Wt[c][k] = proj_W[k][c], bf16, pad c>=50 with 0
        const int c = i >> 9;
        const int k = i & 511;
        const float v = (c < L_) ? projW[k * L_ + c] : 0.f;
        Wt[i] = f2bf(v);
    }
    if (i < (V_ * E_) / 8){                         // bf16 embedding table (same RNE as before)
        const v4f* src = (const v4f*)(we + (size_t)i * 8);
        const v4f a = src[0], b = src[1];
        short8 o;
#pragma unroll
        for (int j = 0; j < 4; ++j){ o[j] = (short)f2bf(a[j]); o[4 + j] = (short)f2bf(b[j]); }
        *(short8*)(we_bf + (size_t)i * 8) = o;
    }
}

// ---------------------------------------------------------------- LSTM recurrence (cooperative, canary-validated)
// Fully async dataflow: producer stores h (fire-and-forget, sc0 sc1 @ MALL);
// consumer loads h[t] chunks and validates against the canary. The entire
// flag path (ack RT + flag store + poll RT + __syncthreads) leaves the chain;
// handoff = last-producer-commit + ~1.5 MALL RT (retry sampling).
//  * per-chunk staleness mask; retries re-issue ONLY stale chunks (r11 fix).
//  * validation: fold chunk's 4 dwords with v_pk_max_u16; stale iff either
//    half of the fold == 0xFFFF. Sound: committed dwords are atomic and
//    valid h (|h|<=1 bf16, or 0) never has a 0xFFFF half.
//  * backoff: 4 RT-paced immediate retries, then s_sleep(1); guard 1<<14
//    (worst case terminates with absmax blowup, never a watchdog hang).
__global__ void __launch_bounds__(256, 1) lstm_kernel(
    const int* __restrict__ q, const int* __restrict__ lengths,
    const unsigned short* __restrict__ we_bf, const float* __restrict__ lstmW,
    const float* __restrict__ lstmB,
    unsigned short* __restrict__ h_all)
{
    const int tid  = threadIdx.x;
    const int blk  = blockIdx.x;     // worker slot 0..31

    const int wv   = tid >> 6;       // 0..3
    const int lane = tid & 63;
    const int nt = wv & 1, mpair = wv >> 1;   // n-half, m-tile pair
    const int l15 = lane & 15, quad = lane >> 4;

    // ---- A-operand mapping (lane&15 = m = z-col in tile; k = quad*8 + j)
    const int hcA0 = blk * 16 + (mpair * 2 + 0) * 4 + (l15 >> 2);
    const int hcA1 = blk * 16 + (mpair * 2 + 1) * 4 + (l15 >> 2);
    const int gA   = l15 & 3;
    const int colA0 = gA * H_ + hcA0;
    const int colA1 = gA * H_ + hcA1;

    short8 AW0[8], AW1[8], AH0[16], AH1[16];
#pragma unroll
    for (int kc = 0; kc < 8; ++kc){     // x-part rows 0..255
        short8 f0, f1;
#pragma unroll
        for (int j = 0; j < 8; ++j){
            const int r = kc * 32 + quad * 8 + j;
            f0[j] = (short)f2bf(lstmW[(size_t)r * 2048 + colA0]);
            f1[j] = (short)f2bf(lstmW[(size_t)r * 2048 + colA1]);
        }
        AW0[kc] = f0; AW1[kc] = f1;
    }
#pragma unroll
    for (int kc = 0; kc < 16; ++kc){    // h-part rows 256..767
        short8 f0, f1;
#pragma unroll
        for (int j = 0; j < 8; ++j){
            const int r = E_ + kc * 32 + quad * 8 + j;
            f0[j] = (short)f2bf(lstmW[(size_t)r * 2048 + colA0]);
            f1[j] = (short)f2bf(lstmW[(size_t)r * 2048 + colA1]);
        }
        AH0[kc] = f0; AH1[kc] = f1;
    }

    // ---- epilogue mapping (lane&15 = n = batch; D row quad*4+reg -> hc=quad, gate=reg)
    const int bE   = nt * 16 + l15;
    const int hcE0 = blk * 16 + (mpair * 2 + 0) * 4 + quad;
    const int hcE1 = blk * 16 + (mpair * 2 + 1) * 4 + quad;
    float bias0[4], bias1[4];
#pragma unroll
    for (int g = 0; g < 4; ++g){ bias0[g] = lstmB[g * H_ + hcE0]; bias1[g] = lstmB[g * H_ + hcE1]; }
    const int lenb = lengths[bE];

    float c0 = 0.f, c1 = 0.f, hp0 = 0.f, hp1 = 0.f;

    // pre-loop x-part for t=0 (cold path)
    v4f accX0 = { bias0[0], bias0[1], bias0[2], bias0[3] };
    v4f accX1 = { bias1[0], bias1[1], bias1[2], bias1[3] };
    {
        const int qv = q[bE * T_];
        const short8* wp = (const short8*)(we_bf + (size_t)qv * E_);
#pragma unroll
        for (int kc = 0; kc < 8; ++kc){
            const short8 eb = wp[kc * 4 + quad];
            accX0 = __builtin_amdgcn_mfma_f32_16x16x32_bf16(AW0[kc], eb, accX0, 0, 0, 0);
            accX1 = __builtin_amdgcn_mfma_f32_16x16x32_bf16(AW1[kc], eb, accX1, 0, 0, 0);
        }
    }

    int qnext = q[bE * T_ + 1];      // q for t+1 (prefetched one iter ahead)

    for (int t = 0; t < T_; ++t){
        // (C) canary-validated h load with SELECTIVE retry: first attempt
        // loads all 16 chunks; retries re-issue only stale ones (per-lane
        // chunk mask). The loads ARE the synchronization.
        const unsigned short* hrow = h_all + (size_t)t * (B_ * H_) + (size_t)bE * H_;
        i4 hbuf[16];
        {
#pragma unroll
            for (int kc = 0; kc < 16; ++kc)
                hbuf[kc] = load16_dev(hrow + kc * 32 + quad * 8);
            wait_vm0();              // also drains our previous h stores / xe
            unsigned stale = 0u;
#pragma unroll
            for (int kc = 0; kc < 16; ++kc){
                unsigned m = 0u;
                asm("v_pk_max_u16 %0, %1, %2" : "=v"(m) : "v"(hbuf[kc][0]), "v"(hbuf[kc][1]));
                unsigned m2 = 0u;
                asm("v_pk_max_u16 %0, %1, %2" : "=v"(m2) : "v"(hbuf[kc][2]), "v"(hbuf[kc][3]));
                asm("v_pk_max_u16 %0, %0, %1" : "+v"(m) : "v"(m2));
                if (((m & 0xFFFFu) == 0xFFFFu) || ((m >> 16) == 0xFFFFu))
                    stale |= (1u << kc);
            }
            int guard = 0;
            while (__ballot(stale != 0u) != 0ull){
                if (++guard > (1 << 14)) break;   // safety valve (absmax-visible)
                if (guard > 4) __builtin_amdgcn_s_sleep(1);
#pragma unroll
                for (int kc = 0; kc < 16; ++kc)
                    if (stale & (1u << kc))
                        hbuf[kc] = load16_dev(hrow + kc * 32 + quad * 8);
                wait_vm0();
                unsigned ns = 0u;
#pragma unroll
                for (int kc = 0; kc < 16; ++kc){
                    if (stale & (1u << kc)){
                        unsigned m = 0u;
                        asm("v_pk_max_u16 %0, %1, %2" : "=v"(m) : "v"(hbuf[kc][0]), "v"(hbuf[kc][1]));
                        unsigned m2 = 0u;
                        asm("v_pk_max_u16 %0, %1, %2" : "=v"(m2) : "v"(hbuf[kc][2]), "v"(hbuf[kc][3]));
                        asm("v_pk_max_u16 %0, %0, %1" : "+v"(m) : "v"(m2));
                        if (((m & 0xFFFFu) == 0xFFFFu) || ((m >> 16) == 0xFFFFu))
                            ns |= (1u << kc);
                    }
                }
                stale = ns;
            }
        }

        // (A) issue bf16 x-row loads for t+1 NOW (plain cached loads): RT
        // hides under the 32 MFMA + gates below.
        short8 xe[8];
        {
            const short8* wp = (const short8*)(we_bf + (size_t)qnext * E_);
#pragma unroll
            for (int kc = 0; kc < 8; ++kc) xe[kc] = wp[kc * 4 + quad];
        }
        const int qnext2 = q[bE * T_ + ((t + 2 < T_) ? (t + 2) : (T_ - 1))];

        // (D) 32 MFMA in 4 independent chains (kc even/odd x 2 tiles)
        v4f a0e = accX0, a1e = accX1;
        v4f a0o = { 0.f, 0.f, 0.f, 0.f }, a1o = { 0.f, 0.f, 0.f, 0.f };
#pragma unroll
        for (int kc = 0; kc < 16; kc += 2){
            union { i4 i; short8 s; } cv0, cv1; cv0.i = hbuf[kc]; cv1.i = hbuf[kc + 1];
            a0e = __builtin_amdgcn_mfma_f32_16x16x32_bf16(AH0[kc],     cv0.s, a0e, 0, 0, 0);
            a1e = __builtin_amdgcn_mfma_f32_16x16x32_bf16(AH1[kc],     cv0.s, a1e, 0, 0, 0);
            a0o = __builtin_amdgcn_mfma_f32_16x16x32_bf16(AH0[kc + 1], cv1.s, a0o, 0, 0, 0);
            a1o = __builtin_amdgcn_mfma_f32_16x16x32_bf16(AH1[kc + 1], cv1.s, a1o, 0, 0, 0);
        }
        const v4f acc0 = a0e + a0o;
        const v4f acc1 = a1e + a1o;

        // (E) gates per tile: i,j,f,o = acc[0..3]; native exp/rcp
        const bool msk = (t < lenb);
        const float cn0 = c0 * fastsig(acc0[2] + 1.0f) + fastsig(acc0[0]) * fasttanh(acc0[1]);
        const float hn0 = fasttanh(cn0) * fastsig(acc0[3]);
        c0 = msk ? cn0 : c0;
        const float h20 = msk ? hn0 : hp0; hp0 = h20;
        const float cn1 = c1 * fastsig(acc1[2] + 1.0f) + fastsig(acc1[0]) * fasttanh(acc1[1]);
        const float hn1 = fasttanh(cn1) * fastsig(acc1[3]);
        c1 = msk ? cn1 : c1;
        const float h21 = msk ? hn1 : hp1; hp1 = h21;

        // (F) pack 4 hc per tile into u64; quad0 stores tile0, quad1 stores
        // tile1. Fire-and-forget: consumers validate; no ack/flag/sync.
        const unsigned hv0 = f2bf(h20), hv1 = f2bf(h21);
        const int a0 = __shfl((int)hv0, l15, 64),      a1 = __shfl((int)hv0, l15 + 16, 64);
        const int a2 = __shfl((int)hv0, l15 + 32, 64), a3 = __shfl((int)hv0, l15 + 48, 64);
        const int b0 = __shfl((int)hv1, l15, 64),      b1 = __shfl((int)hv1, l15 + 16, 64);
        const int b2 = __shfl((int)hv1, l15 + 32, 64), b3 = __shfl((int)hv1, l15 + 48, 64);
        unsigned short* dstBase = h_all + (size_t)(t + 1) * (B_ * H_) + (size_t)bE * H_
                                + blk * 16 + mpair * 8;
        if (quad == 0){
            const u64 pk = (u64)(unsigned short)a0 | ((u64)(unsigned short)a1 << 16)
                         | ((u64)(unsigned short)a2 << 32) | ((u64)(unsigned short)a3 << 48);
            store8_dev(dstBase, pk);
        } else if (quad == 1){
            const u64 pk = (u64)(unsigned short)b0 | ((u64)(unsigned short)b1 << 16)
                         | ((u64)(unsigned short)b2 << 32) | ((u64)(unsigned short)b3 << 48);
            store8_dev(dstBase + 4, pk);
        }

        // (G) tail: 16 MFMA on prefetched bf16 x-row (runs in the shadow of
        // consumers' validation of our stores)
        if (t + 1 < T_){
            accX0 = (v4f){ bias0[0], bias0[1], bias0[2], bias0[3] };
            accX1 = (v4f){ bias1[0], bias1[1], bias1[2], bias1[3] };
#pragma unroll
            for (int kc = 0; kc < 8; ++kc){
                accX0 = __builtin_amdgcn_mfma_f32_16x16x32_bf16(AW0[kc], xe[kc], accX0, 0, 0, 0);
                accX1 = __builtin_amdgcn_mfma_f32_16x16x32_bf16(AW1[kc], xe[kc], accX1, 0, 0, 0);
            }
        }
        qnext = qnext2;
    }
}

// ---------------------------------------------------------------- projection + relu + log-softmax + xent
// h reads via sc0 sc1 (preloaded, one wait): lstm stored h bypassing L2, and
// init cached canary lines — plain loads could hit stale canary in an L2 that
// isn't invalidated at dispatch. MALL reads are unconditionally correct.
__global__ void __launch_bounds__(256) loss_kernel(
    const int* __restrict__ a, const int* __restrict__ lengths,
    const float* __restrict__ projB,
    const unsigned short* __restrict__ h_all,
    const unsigned short* __restrict__ Wt,
    float* __restrict__ out)
{
    const int tid = threadIdx.x;
    const int wv = tid >> 6, lane = tid & 63;
    const int l15 = lane & 15, quad = lane >> 4;
    const int wgid = blockIdx.x * 4 + wv;            // 0..1023
    const int row0 = wgid * 16;

    const int rowA = row0 + l15;
    const int bA = rowA >> 9, tA = rowA & 511;
    const unsigned short* hrow = h_all + ((size_t)(tA + 1) * B_ + bA) * H_;

    i4 afb[16];
#pragma unroll
    for (int kc = 0; kc < 16; ++kc)
        afb[kc] = load16_dev(hrow + kc * 32 + quad * 8);
    wait_vm0();

    v4f acc[4] = { {0,0,0,0}, {0,0,0,0}, {0,0,0,0}, {0,0,0,0} };
#pragma unroll
    for (int kc = 0; kc < 16; ++kc){
        union { i4 i; short8 s; } u; u.i = afb[kc];
#pragma unroll
        for (int ntl = 0; ntl < 4; ++ntl){
            const short8 bf = *(const short8*)(Wt + (size_t)(ntl * 16 + l15) * H_ + kc * 32 + quad * 8);
            acc[ntl] = __builtin_amdgcn_mfma_f32_16x16x32_bf16(u.s, bf, acc[ntl], 0, 0, 0);
        }
    }

    float pb[4]; bool cv[4];
#pragma unroll
    for (int ntl = 0; ntl < 4; ++ntl){
        const int c = ntl * 16 + l15;
        cv[ntl] = (c < L_);
        pb[ntl] = cv[ntl] ? projB[c] : 0.f;
    }

#pragma unroll
    for (int r = 0; r < 4; ++r){
        const int row = row0 + quad * 4 + r;
        const int b = row >> 9, t = row & 511;
        const int len = lengths[b];
        const bool valid = (t < len);

        float lv[4];
#pragma unroll
        for (int ntl = 0; ntl < 4; ++ntl)
            lv[ntl] = fmaxf(acc[ntl][r] + pb[ntl], 0.f);   // relu(logits)

        float mx = -1e30f;
#pragma unroll
        for (int ntl = 0; ntl < 4; ++ntl) if (cv[ntl]) mx = fmaxf(mx, lv[ntl]);
        mx = qredmax(mx);
        float se = 0.f;
#pragma unroll
        for (int ntl = 0; ntl < 4; ++ntl) if (cv[ntl]) se += expf(lv[ntl] - mx);
        se = qredsum(se);
        const int lbl = a[row];
        float cand = 0.f;
#pragma unroll
        for (int ntl = 0; ntl < 4; ++ntl) if (ntl * 16 + l15 == lbl) cand = lv[ntl];
        const float llbl = qredsum(cand);

        if (valid && l15 == 0){
            const float xent = logf(se) + mx - llbl;      // -log_softmax[label]
            atomicAdd(out, xent / ((float)len * 32.0f));
        }
    }
}

// ---------------------------------------------------------------- launch
extern "C" void kernel_launch(void* const* d_in, const int* in_sizes, int n_in,
                              void* d_out, int out_size, void* d_ws, size_t ws_size,
                              hipStream_t stream)
{
    const int*   q   = (const int*)d_in[0];
    const int*   a   = (const int*)d_in[1];
    const int*   len = (const int*)d_in[2];
    const float* we  = (const float*)d_in[3];
    const float* lW  = (const float*)d_in[4];
    const float* lB  = (const float*)d_in[5];
    const float* pW  = (const float*)d_in[6];
    const float* pB  = (const float*)d_in[7];
    float* out = (float*)d_out;

    unsigned char* ws = (unsigned char*)d_ws;
    unsigned short* h_all = (unsigned short*)(ws + 8192);            // 513*32*512*2 B = 16.84 MB
    unsigned short* Wt    = (unsigned short*)(ws + 8192 + (size_t)(T_ + 1) * B_ * H_ * 2);  // 64 KiB
    unsigned short* we_bf = (unsigned short*)(ws + 8192 + (size_t)(T_ + 1) * B_ * H_ * 2 + 65536); // 25.6 MB

    init_kernel<<<dim3(6400), dim3(256), 0, stream>>>(pW, we, out, h_all, Wt, we_bf);

    {
        const int* q_ = q; const int* len_ = len; const unsigned short* we_ = we_bf;
        const float* lW_ = lW; const float* lB_ = lB;
        unsigned short* h_ = h_all;
        void* args[] = { (void*)&q_, (void*)&len_, (void*)&we_, (void*)&lW_,
                         (void*)&lB_, (void*)&h_ };
        hipLaunchCooperativeKernel((void*)lstm_kernel, dim3(NGRID), dim3(256),
                                   args, 0, stream);
    }

    loss_kernel<<<dim3(256), dim3(256), 0, stream>>>(a, len, pB, h_all, Wt, out);
}